// Round 9
// baseline (2578.196 us; speedup 1.0000x reference)
//
#include <hip/hip_runtime.h>
#include <stdint.h>

#define BB 8
#define NN 4096
#define FF 512
#define KK 100
#define K2 112   // K padded to 7*16 for MFMA tiles

// DIAGNOSTIC ROUND: rep counts to surface each kernel above the ~315us fill wall.
#define R_K1 6
#define R_K2 4
#define R_K3 8
#define R_K4 20

typedef __attribute__((ext_vector_type(8))) short short8;
typedef __attribute__((ext_vector_type(4))) float f32x4;

union CV8 { uint4 u; short8 s; };

__device__ __forceinline__ unsigned short f2b(float f){
  unsigned u = __float_as_uint(f);
  return (unsigned short)((u + 0x7FFFu + ((u >> 16) & 1u)) >> 16);  // RNE fp32->bf16
}

__device__ __forceinline__ unsigned cvt2(float lo, float hi){
  unsigned r;
  asm("v_cvt_pk_bf16_f32 %0, %1, %2" : "=v"(r) : "v"(lo), "v"(hi));
  return r;
}

__device__ __forceinline__ f32x4 mfma16(short8 a, short8 b, f32x4 c){
  return __builtin_amdgcn_mfma_f32_16x16x32_bf16(a, b, c, 0, 0, 0);
}

__device__ __forceinline__ void gll16(const void* g, unsigned char* lds_base_plus_off){
  __builtin_amdgcn_global_load_lds(
      (const __attribute__((address_space(1))) unsigned int*)g,
      (__attribute__((address_space(3))) unsigned int*)lds_base_plus_off,
      16, 0, 0);
}

// ---------------- K0
__global__ void k0_wconv(const float* __restrict__ W, unsigned short* __restrict__ Wb,
                         float* __restrict__ dout){
  int i = blockIdx.x * 256 + threadIdx.x;
  if (i == 0) dout[489600] = 0.f;
  if (i >= K2 * FF) return;
  int k = i >> 9;
  Wb[i] = (k < KK) ? f2b(W[i]) : (unsigned short)0;
}

// ---------------- K1 (x R_K1 reps)
__launch_bounds__(256)
__global__ void k1_logits(const float* __restrict__ x, const float* __restrict__ bias,
                          const unsigned short* __restrict__ Wb,
                          unsigned short* __restrict__ sT, unsigned short* __restrict__ xT,
                          float* __restrict__ ssum){
  __shared__ unsigned short xtile[64 * 40];
  __shared__ unsigned short slds[112 * 72];
  const int t = threadIdx.x, bx = blockIdx.x;
  const int b = bx & 7, n0 = ((bx >> 3) & 63) << 6;
  const int w = t >> 6, ln15 = t & 15, g = (t & 63) >> 4;
  const float* xb = x + ((size_t)b * NN + n0) * FF;
  const int r = t >> 2, c0 = (t & 3) << 3;

  #pragma unroll 1
  for (int rep = 0; rep < R_K1; ++rep){
  __syncthreads();
  f32x4 acc[7];
  #pragma unroll
  for (int i = 0; i < 7; ++i) acc[i] = (f32x4){0.f, 0.f, 0.f, 0.f};

  float4 a0 = ((const float4*)(xb + (size_t)r * FF + c0))[0];
  float4 a1 = ((const float4*)(xb + (size_t)r * FF + c0))[1];

  #pragma unroll 1
  for (int fs = 0; fs < 16; ++fs){
    const int f0 = fs << 5;
    uint4 pk;
    pk.x = (unsigned)f2b(a0.x) | ((unsigned)f2b(a0.y) << 16);
    pk.y = (unsigned)f2b(a0.z) | ((unsigned)f2b(a0.w) << 16);
    pk.z = (unsigned)f2b(a1.x) | ((unsigned)f2b(a1.y) << 16);
    pk.w = (unsigned)f2b(a1.z) | ((unsigned)f2b(a1.w) << 16);
    *(uint4*)&xtile[r * 40 + c0] = pk;
    __syncthreads();
    {
      const int fn = (fs + 1 < 16) ? fs + 1 : 15;
      const float4* srcn = (const float4*)(xb + (size_t)r * FF + (fn << 5) + c0);
      float4 n0v = srcn[0], n1v = srcn[1];
      short8 av = *(const short8*)&xtile[(16 * w + ln15) * 40 + 8 * g];
      #pragma unroll
      for (int kf = 0; kf < 7; ++kf){
        short8 bv = *(const short8*)(Wb + (size_t)(16 * kf + ln15) * FF + f0 + 8 * g);
        acc[kf] = mfma16(av, bv, acc[kf]);
      }
      const int fi = t >> 3, nc = t & 7;
      uint4 o;
      o.x = (unsigned)xtile[(8*nc+0)*40+fi] | ((unsigned)xtile[(8*nc+1)*40+fi] << 16);
      o.y = (unsigned)xtile[(8*nc+2)*40+fi] | ((unsigned)xtile[(8*nc+3)*40+fi] << 16);
      o.z = (unsigned)xtile[(8*nc+4)*40+fi] | ((unsigned)xtile[(8*nc+5)*40+fi] << 16);
      o.w = (unsigned)xtile[(8*nc+6)*40+fi] | ((unsigned)xtile[(8*nc+7)*40+fi] << 16);
      *(uint4*)(xT + ((size_t)b * FF + f0 + fi) * NN + n0 + 8 * nc) = o;
      a0 = n0v; a1 = n1v;
    }
    __syncthreads();
  }

  #pragma unroll
  for (int rr = 0; rr < 4; ++rr){
    const int nloc = 16 * w + 4 * g + rr;
    float lg[7];
    float m = -1e30f;
    #pragma unroll
    for (int kf = 0; kf < 7; ++kf){
      int k = 16 * kf + ln15;
      float v = (k < KK) ? (acc[kf][rr] + bias[k]) : -1e30f;
      lg[kf] = v; m = fmaxf(m, v);
    }
    #pragma unroll
    for (int d = 1; d < 16; d <<= 1) m = fmaxf(m, __shfl_xor(m, d, 16));
    float sum = 0.f, sq = 0.f;
    float ev[7];
    #pragma unroll
    for (int kf = 0; kf < 7; ++kf){
      int k = 16 * kf + ln15;
      float e = (k < KK) ? __expf(lg[kf] - m) : 0.f;
      ev[kf] = e; sum += e; sq += e * e;
    }
    #pragma unroll
    for (int d = 1; d < 16; d <<= 1){ sum += __shfl_xor(sum, d, 16); sq += __shfl_xor(sq, d, 16); }
    float inv = 1.f / sum;
    #pragma unroll
    for (int kf = 0; kf < 7; ++kf)
      slds[(16 * kf + ln15) * 72 + nloc] = f2b(ev[kf] * inv);
    if (ln15 == 0) ssum[b * NN + n0 + nloc] = sq * inv * inv;
  }
  __syncthreads();
  for (int c = t; c < 112 * 8; c += 256){
    int row = c >> 3, nc = c & 7;
    uint4 v = *(const uint4*)&slds[row * 72 + 8 * nc];
    if (row == 111) v.x = v.y = v.z = v.w = 0x3F803F80u;
    *(uint4*)(sT + ((size_t)b * K2 + row) * NN + n0 + 8 * nc) = v;
  }
  }  // rep
}

// ---------------- K2 (x R_K2 reps)
__launch_bounds__(256, 2)
__global__ void k2_adj(const float* __restrict__ adj, const unsigned short* __restrict__ sT,
                       unsigned short* __restrict__ AsT, float* __restrict__ deg){
  __shared__ __align__(16) unsigned char ldsbuf[73728];   // 3 x (A 16KB + B 8KB)
  const int t = threadIdx.x, bx = blockIdx.x;
  const int b = bx & 7, n0 = (bx >> 3) << 7;
  const int w = t >> 6, ln15 = t & 15, g = (t & 63) >> 4;

  const int rA = t >> 3, cA = t & 7;
  const int rB = t >> 2, cB = t & 3;
  const float* aA = adj + ((size_t)(b * NN + n0 + rA)) * NN + ((cA ^ (rA & 7)) << 2);
  const unsigned short* sB = sT + ((size_t)(b * K2 + rB)) * NN + ((cB ^ (rB & 3)) << 3);

#define ISSUE(S) {                                                         \
    const unsigned st_ = (unsigned)((S) % 3) * 24576u + (unsigned)w * 1024u; \
    const size_t lo_ = (size_t)(S) * 32;                                   \
    gll16(aA + lo_,                  ldsbuf + st_);                        \
    gll16(aA + lo_ + (size_t)32*NN,  ldsbuf + st_ + 4096);                 \
    gll16(aA + lo_ + (size_t)64*NN,  ldsbuf + st_ + 8192);                 \
    gll16(aA + lo_ + (size_t)96*NN,  ldsbuf + st_ + 12288);                \
    gll16(sB + lo_,                  ldsbuf + st_ + 16384);                \
    gll16(sB + lo_ + (size_t)64*NN,  ldsbuf + st_ + 20480);                \
  }

#define COMPUTE(S) {                                                       \
    const unsigned char* Ab_ = ldsbuf + ((S) % 3) * 24576;                 \
    const unsigned char* Bb_ = Ab_ + 16384;                                \
    const int lr = 16 * w + ln15;                                          \
    float4 af0 = *(const float4*)(Ab_ + (size_t)(lr * 8 + ((2 * g)     ^ (lr & 7))) * 16); \
    float4 af1 = *(const float4*)(Ab_ + (size_t)(lr * 8 + ((2 * g + 1) ^ (lr & 7))) * 16); \
    uint4 pk;                                                              \
    pk.x = cvt2(af0.x, af0.y); pk.y = cvt2(af0.z, af0.w);                  \
    pk.z = cvt2(af1.x, af1.y); pk.w = cvt2(af1.z, af1.w);                  \
    CV8 cv; cv.u = pk;                                                     \
    short8 av = cv.s;                                                      \
    _Pragma("unroll")                                                      \
    for (int kf = 0; kf < 7; ++kf){                                        \
      int rb_ = 16 * kf + ln15;                                            \
      CV8 bb; bb.u = *(const uint4*)(Bb_ + (size_t)(rb_ * 4 + (g ^ (rb_ & 3))) * 16); \
      acc[kf] = mfma16(av, bb.s, acc[kf]);                                 \
    }                                                                      \
  }

  #pragma unroll 1
  for (int rep = 0; rep < R_K2; ++rep){
  __syncthreads();
  f32x4 acc[7];
  #pragma unroll
  for (int i = 0; i < 7; ++i) acc[i] = (f32x4){0.f, 0.f, 0.f, 0.f};

  ISSUE(0) ISSUE(1) ISSUE(2)

  #pragma unroll 1
  for (int s = 0; s < 125; ++s){
    asm volatile("s_waitcnt vmcnt(12)" ::: "memory");
    __builtin_amdgcn_sched_barrier(0);
    __builtin_amdgcn_s_barrier();
    COMPUTE(s)
    __builtin_amdgcn_sched_barrier(0);
    __builtin_amdgcn_s_barrier();
    ISSUE(s + 3)
  }
  asm volatile("s_waitcnt vmcnt(12)" ::: "memory");
  __builtin_amdgcn_sched_barrier(0);
  __builtin_amdgcn_s_barrier();
  COMPUTE(125)
  __builtin_amdgcn_sched_barrier(0);
  __builtin_amdgcn_s_barrier();
  asm volatile("s_waitcnt vmcnt(6)" ::: "memory");
  __builtin_amdgcn_sched_barrier(0);
  __builtin_amdgcn_s_barrier();
  COMPUTE(126)
  __builtin_amdgcn_sched_barrier(0);
  __builtin_amdgcn_s_barrier();
  asm volatile("s_waitcnt vmcnt(0)" ::: "memory");
  __builtin_amdgcn_sched_barrier(0);
  __builtin_amdgcn_s_barrier();
  COMPUTE(127)

  if (ln15 == 15)
    *(f32x4*)(deg + (size_t)b * NN + n0 + 16 * w + 4 * g) = acc[6];
  #pragma unroll
  for (int kf = 0; kf < 7; ++kf){
    int k = 16 * kf + ln15;
    uint2 ov;
    ov.x = cvt2(acc[kf][0], acc[kf][1]);
    ov.y = cvt2(acc[kf][2], acc[kf][3]);
    *(uint2*)(AsT + ((size_t)b * K2 + k) * NN + n0 + 16 * w + 4 * g) = ov;
  }
  }  // rep
#undef ISSUE
#undef COMPUTE
}

// ---------------- K3 fused (x R_K3 reps)
__launch_bounds__(256, 2)
__global__ void k3_fused(const unsigned short* __restrict__ sT,
                         const unsigned short* __restrict__ xT,
                         const unsigned short* __restrict__ AsT,
                         float* __restrict__ outp, float* __restrict__ kkp){
  __shared__ __align__(16) unsigned short at[112 * 136];
  __shared__ __align__(16) unsigned short bt[128 * 136];
  const int t = threadIdx.x, bx = blockIdx.x;
  const int w = t >> 6, ln15 = t & 15, g = (t & 63) >> 4;
  const int srow16 = t >> 4, scol8 = (t & 15) << 3;

  if (bx < 256){
    const int b = bx & 7, ft = (bx >> 3) & 3, nc = bx >> 5;
    const unsigned short* Ab = sT + (size_t)b * K2 * NN;
    const unsigned short* Bb = xT + ((size_t)b * FF + ft * 128) * NN;
    #pragma unroll 1
    for (int rep = 0; rep < R_K3; ++rep){
    __syncthreads();
    f32x4 acc[7][2];
    #pragma unroll
    for (int i = 0; i < 7; ++i){ acc[i][0] = (f32x4){0,0,0,0}; acc[i][1] = (f32x4){0,0,0,0}; }
    #pragma unroll 1
    for (int rd = 0; rd < 4; ++rd){
      const int l0 = nc * 512 + rd * 128;
      if (rd) __syncthreads();
      #pragma unroll
      for (int p = 0; p < 15; ++p){
        int crow = srow16 + 16 * p;
        if (crow < 112)
          *(uint4*)&at[crow * 136 + scol8] = *(const uint4*)(Ab + (size_t)crow * NN + l0 + scol8);
        else
          *(uint4*)&bt[(crow - 112) * 136 + scol8] =
            *(const uint4*)(Bb + (size_t)(crow - 112) * NN + l0 + scol8);
      }
      __syncthreads();
      #pragma unroll
      for (int s = 0; s < 4; ++s){
        const int ll = s * 32 + 8 * g;
        short8 bv0 = *(const short8*)&bt[(32 * w + ln15) * 136 + ll];
        short8 bv1 = *(const short8*)&bt[(32 * w + 16 + ln15) * 136 + ll];
        #pragma unroll
        for (int mf = 0; mf < 7; ++mf){
          short8 av = *(const short8*)&at[(16 * mf + ln15) * 136 + ll];
          acc[mf][0] = mfma16(av, bv0, acc[mf][0]);
          acc[mf][1] = mfma16(av, bv1, acc[mf][1]);
        }
      }
    }
    const int f0 = ft * 128 + 32 * w;
    float* ob = outp + ((size_t)(bx >> 5) * BB + b) * (K2 * FF);
    #pragma unroll
    for (int mf = 0; mf < 7; ++mf)
      #pragma unroll
      for (int i = 0; i < 2; ++i)
        #pragma unroll
        for (int rr = 0; rr < 4; ++rr){
          int k = 16 * mf + 4 * g + rr;
          ob[(size_t)k * FF + f0 + 16 * i + ln15] = acc[mf][i][rr];
        }
    }  // rep
  } else {
    const int idx = bx - 256;
    const int b = idx & 7, nc = (idx >> 3) & 15, mat = idx >> 7;
    const unsigned short* Ab = sT + (size_t)b * K2 * NN;
    const unsigned short* Bb = (mat ? sT : AsT) + (size_t)b * K2 * NN;
    const int nf0 = 2 * w;
    const int nf1 = (2 * w + 1 < 7) ? 2 * w + 1 : 0;
    #pragma unroll 1
    for (int rep = 0; rep < R_K3; ++rep){
    __syncthreads();
    f32x4 acc[7][2];
    #pragma unroll
    for (int i = 0; i < 7; ++i){ acc[i][0] = (f32x4){0,0,0,0}; acc[i][1] = (f32x4){0,0,0,0}; }
    #pragma unroll 1
    for (int rd = 0; rd < 2; ++rd){
      const int l0 = nc * 256 + rd * 128;
      if (rd) __syncthreads();
      #pragma unroll
      for (int p = 0; p < 14; ++p){
        int crow = srow16 + 16 * p;
        if (crow < 112)
          *(uint4*)&at[crow * 136 + scol8] = *(const uint4*)(Ab + (size_t)crow * NN + l0 + scol8);
        else
          *(uint4*)&bt[(crow - 112) * 136 + scol8] =
            *(const uint4*)(Bb + (size_t)(crow - 112) * NN + l0 + scol8);
      }
      __syncthreads();
      #pragma unroll
      for (int s = 0; s < 4; ++s){
        const int ll = s * 32 + 8 * g;
        short8 bv0 = *(const short8*)&bt[(16 * nf0 + ln15) * 136 + ll];
        short8 bv1 = *(const short8*)&bt[(16 * nf1 + ln15) * 136 + ll];
        #pragma unroll
        for (int mf = 0; mf < 7; ++mf){
          short8 av = *(const short8*)&at[(16 * mf + ln15) * 136 + ll];
          acc[mf][0] = mfma16(av, bv0, acc[mf][0]);
          acc[mf][1] = mfma16(av, bv1, acc[mf][1]);
        }
      }
    }
    float* ob = kkp + ((size_t)(mat * 16 + nc) * BB + b) * (K2 * K2);
    #pragma unroll
    for (int mf = 0; mf < 7; ++mf)
      #pragma unroll
      for (int rr = 0; rr < 4; ++rr){
        int k = 16 * mf + 4 * g + rr;
        ob[(size_t)k * K2 + 16 * nf0 + ln15] = acc[mf][0][rr];
        if (2 * w + 1 < 7)
          ob[(size_t)k * K2 + 16 * nf1 + ln15] = acc[mf][1][rr];
      }
    }  // rep
  }
}

// ---------------- K4 fused (x R_K4 reps; scalar atomics on last rep only)
union K4S {
  struct { float r1[256]; float r2[256]; } a;
  struct { float vbuf[BB * FF]; float r1[256]; float r2[256]; } bsec;
  struct { float oa[KK * KK]; float sr[KK * KK]; float dvals[KK]; float red[256]; } c;
};

__global__ void k4_fused(const float* __restrict__ deg, const float* __restrict__ ssum,
                         const float* __restrict__ kkp, const float* __restrict__ outp,
                         const float* __restrict__ gamma, const float* __restrict__ beta,
                         float* __restrict__ dout){
  __shared__ K4S u;
  const int t = threadIdx.x, bx = blockIdx.x;
  #pragma unroll 1
  for (int rep = 0; rep < R_K4; ++rep){
  __syncthreads();
  if (bx < 8){
    const int b = bx;
    float p = 0.f;
    for (int n = t; n < NN; n += 256) p += deg[(size_t)b * NN + n] * ssum[(size_t)b * NN + n];
    float q = 0.f;
    for (int e = t; e < 16 * KK; e += 256){
      int nc = e / KK, k = e - nc * KK;
      q += kkp[((size_t)nc * BB + b) * (K2 * K2) + (size_t)k * K2 + k];
    }
    u.a.r1[t] = p; u.a.r2[t] = q; __syncthreads();
    for (int s = 128; s > 0; s >>= 1){
      if (t < s){ u.a.r1[t] += u.a.r1[t + s]; u.a.r2[t] += u.a.r2[t + s]; }
      __syncthreads();
    }
    if (t == 0 && rep == R_K4 - 1) atomicAdd(&dout[489600], -(u.a.r2[0] / u.a.r1[0]) * 0.125f);
  } else if (bx < 108){
    const int k = bx - 8;
    float s1 = 0.f, s2v = 0.f;
    for (int j = t; j < BB * FF; j += 256){
      int b = j >> 9, f = j & (FF - 1);
      float v = 0.f;
      #pragma unroll
      for (int nc = 0; nc < 8; ++nc)
        v += outp[((size_t)nc * BB + b) * (K2 * FF) + (size_t)k * FF + f];
      u.bsec.vbuf[j] = v; s1 += v; s2v += v * v;
    }
    u.bsec.r1[t] = s1; u.bsec.r2[t] = s2v; __syncthreads();
    for (int s = 128; s > 0; s >>= 1){
      if (t < s){ u.bsec.r1[t] += u.bsec.r1[t + s]; u.bsec.r2[t] += u.bsec.r2[t + s]; }
      __syncthreads();
    }
    const float mean = u.bsec.r1[0] * (1.f / (BB * FF));
    const float var = u.bsec.r2[0] * (1.f / (BB * FF)) - mean * mean;
    const float sc = gamma[k] * rsqrtf(var + 1e-5f);
    const float sh = beta[k] - mean * sc;
    for (int j = t; j < BB * FF; j += 256){
      int b = j >> 9, f = j & (FF - 1);
      dout[((size_t)b * KK + k) * FF + f] = u.bsec.vbuf[j] * sc + sh;
    }
  } else {
    const int b = bx - 108;
    for (int e = t; e < KK * KK; e += 256){
      int k = e / KK, l = e - k * KK;
      float so = 0.f, ss = 0.f;
      #pragma unroll
      for (int nc = 0; nc < 16; ++nc){
        so += kkp[((size_t)nc * BB + b) * (K2 * K2) + (size_t)k * K2 + l];
        ss += kkp[((size_t)(16 + nc) * BB + b) * (K2 * K2) + (size_t)k * K2 + l];
      }
      u.c.oa[e] = so; u.c.sr[e] = ss;
    }
    __syncthreads();
    if (t < KK){
      float s = 0.f;
      for (int l = 0; l < KK; ++l) if (l != t) s += u.c.oa[t * KK + l];
      u.c.dvals[t] = sqrtf(s) + 1e-15f;
    }
    float p = 0.f;
    for (int e = t; e < KK * KK; e += 256) p += u.c.sr[e] * u.c.sr[e];
    u.c.red[t] = p; __syncthreads();
    for (int s = 128; s > 0; s >>= 1){ if (t < s) u.c.red[t] += u.c.red[t + s]; __syncthreads(); }
    const float inv = 1.f / sqrtf(u.c.red[0]);
    __syncthreads();
    float q = 0.f;
    for (int e = t; e < KK * KK; e += 256){
      int k = e / KK, l = e - k * KK;
      float ov = (k == l) ? 0.f : u.c.oa[e];
      dout[409600 + (size_t)b * KK * KK + e] = ov / (u.c.dvals[k] * u.c.dvals[l]);
      float sv = u.c.sr[e] * inv - ((k == l) ? 0.1f : 0.f);
      q += sv * sv;
    }
    u.c.red[t] = q; __syncthreads();
    for (int s = 128; s > 0; s >>= 1){ if (t < s) u.c.red[t] += u.c.red[t + s]; __syncthreads(); }
    if (t == 0 && rep == R_K4 - 1) atomicAdd(&dout[489600], sqrtf(u.c.red[0]) * 0.125f);
  }
  }  // rep
}

extern "C" void kernel_launch(void* const* d_in, const int* in_sizes, int n_in,
                              void* d_out, int out_size, void* d_ws, size_t ws_size,
                              hipStream_t stream){
  const float* x     = (const float*)d_in[0];
  const float* adj   = (const float*)d_in[1];
  const float* W     = (const float*)d_in[3];
  const float* bias  = (const float*)d_in[4];
  const float* gamma = (const float*)d_in[5];
  const float* beta  = (const float*)d_in[6];
  float* out = (float*)d_out;
  char* ws = (char*)d_ws;

  unsigned short* sT  = (unsigned short*)(ws + 0);
  unsigned short* xT  = (unsigned short*)(ws + 7340032);
  unsigned short* AsT = (unsigned short*)(ws + 40894464);
  float* deg    = (float*)(ws + 48234496);
  float* ssum   = (float*)(ws + 48365568);
  float* outp   = (float*)(ws + 48496640);
  float* kkp    = (float*)(ws + 63176704);
  unsigned short* Wb = (unsigned short*)(ws + 76021760);

  k0_wconv<<<224, 256, 0, stream>>>(W, Wb, out);
  k1_logits<<<512, 256, 0, stream>>>(x, bias, Wb, sT, xT, ssum);
  k2_adj<<<256, 256, 0, stream>>>(adj, sT, AsT, deg);
  k3_fused<<<512, 256, 0, stream>>>(sT, xT, AsT, outp, kkp);
  k4_fused<<<116, 256, 0, stream>>>(deg, ssum, kkp, outp, gamma, beta, out);
}